// Round 6
// baseline (464.534 us; speedup 1.0000x reference)
//
#include <hip/hip_runtime.h>

// UniversalGRU: 2-layer GRU (B=2048, T=512, D=1, H=64) + FC(64->1).
// R13 = R12 dataflow (h-as-B-operand, weight-stationary, tau-single split,
// lane-local recurrence) with the PER-STEP BARRIER REPLACED by flag-based
// producer/consumer sync. R12 measured: step = 1390 cyc vs 520 cyc of
// per-SIMD issue (37% util) -- the 8-wave lockstep barrier charged every
// wave with the last-arriver's skew plus a cold-start dependency chain.
// R13: per-wave LDS sequence flags (seqA[4], seqB[4]).
//   L0-tau step s  waits min(seqA) >= s   (peers' hA(s-1))
//                  and  min(seqB) >= s-1  (hAq buffer overwrite guard)
//   L1-tau iter t  waits min(seqA) >= t   (hA(t-1) ready)
//                  and  min(seqB) >= t-1  (peers' hB(t-2))
// Writer protocol: ds_write h-quarter -> s_waitcnt lgkmcnt(0) -> volatile
// flag store (DS pipe is per-wave in-order: flag visible => data visible).
// Deadlock-free by induction (L0 step s enabled by seqA=s & seqB>=s-1;
// completing it enables L1 iter s+1; which enables L0 step s+2; all 8
// waves of the block are always co-resident at 1 block/CU).
// 128 blocks x 512 threads, one initial + one final __syncthreads only.

#define T_LEN 512
#define BROWS 16
#define XPAD  513
#define LOG2E 1.44269504088896f

typedef float          f32x4 __attribute__((ext_vector_type(4)));
typedef __bf16         bf16x8 __attribute__((ext_vector_type(8)));
typedef unsigned short us8   __attribute__((ext_vector_type(8)));
typedef unsigned int   ui4   __attribute__((ext_vector_type(4)));
typedef unsigned int   ui2   __attribute__((ext_vector_type(2)));
typedef unsigned short ushort_t;

__device__ __forceinline__ float bf2f(ushort_t b){
    unsigned int u = ((unsigned int)b) << 16;
    return __uint_as_float(u);
}
__device__ __forceinline__ ushort_t f2bf(float f){
    unsigned int u = __float_as_uint(f);
    u = (u + 0x7FFFu + ((u >> 16) & 1u)) >> 16;   // RNE
    return (ushort_t)u;
}
__device__ __forceinline__ float ld_any(const void* p, int i, bool f32){
    return f32 ? ((const float*)p)[i] : bf2f(((const ushort_t*)p)[i]);
}
__device__ __forceinline__ float exp2_fast(float x){
#if __has_builtin(__builtin_amdgcn_exp2f)
    return __builtin_amdgcn_exp2f(x);          // v_exp_f32 (2^x)
#else
    return __expf(0.6931471805599453f * x);
#endif
}
__device__ __forceinline__ float rcp_fast(float x){
#if __has_builtin(__builtin_amdgcn_rcpf)
    return __builtin_amdgcn_rcpf(x);           // v_rcp_f32
#else
    return __fdividef(1.0f, x);
#endif
}
// sigma(x) with pre-scaled argument t = log2e * x
__device__ __forceinline__ float sigm2(float t){
    return rcp_fast(1.0f + exp2_fast(-t));
}
// tanh(y) with pre-scaled argument t = 2*log2e * y
__device__ __forceinline__ float tanh2(float t){
    return fmaf(-2.0f, rcp_fast(exp2_fast(t) + 1.0f), 1.0f);
}
__device__ __forceinline__ f32x4 mfma16(bf16x8 a, bf16x8 b, f32x4 c){
    return __builtin_amdgcn_mfma_f32_16x16x32_bf16(a, b, c, 0, 0, 0);
}
// packed f32x2 -> bf16x2 (RNE) in one instruction
__device__ __forceinline__ unsigned int cvtpk(float lo, float hi){
    unsigned int r;
    asm("v_cvt_pk_bf16_f32 %0, %1, %2" : "=v"(r) : "v"(lo), "v"(hi));
    return r;
}
// A-fragment: 8 contiguous k's of W[n][k], pre-scaled then bf16-rounded.
__device__ __forceinline__ bf16x8 mk_frag(const void* W, int n, int kb, bool f32, float sc){
    us8 tmp;
    #pragma unroll
    for (int j = 0; j < 8; ++j){
        float v = f32 ? ((const float*)W)[n * 64 + kb + j]
                      : bf2f(((const ushort_t*)W)[n * 64 + kb + j]);
        tmp[j] = f2bf(v * sc);
    }
    return __builtin_bit_cast(bf16x8, tmp);
}
// Poll: block until min(sa[0..3]) >= na  AND  min(sb[0..3]) >= nb.
// All lanes read the same addresses (LDS broadcast, conflict-free).
__device__ __forceinline__ void wait_flags(volatile int* sa, int na,
                                           volatile int* sb, int nb){
    for (;;){
        int a0 = sa[0], a1 = sa[1], a2 = sa[2], a3 = sa[3];
        int b0 = sb[0], b1 = sb[1], b2 = sb[2], b3 = sb[3];
        int ma = min(min(a0, a1), min(a2, a3));
        int mb = min(min(b0, b1), min(b2, b3));
        if (ma >= na && mb >= nb) break;
        __builtin_amdgcn_s_sleep(1);
    }
    asm volatile("" ::: "memory");   // order subsequent LDS reads after poll
}
// Publish: drain this wave's ds_write, then volatile flag store (lane 0).
__device__ __forceinline__ void post_flag(volatile int* slot, int v, int lane){
    asm volatile("s_waitcnt lgkmcnt(0)" ::: "memory");
    if (lane == 0) *slot = v;
}

__global__ __launch_bounds__(512, 2) void gru_fused(
    const void* __restrict__ xv,
    const void* __restrict__ Wih0, const void* __restrict__ Whh0,
    const void* __restrict__ bih0, const void* __restrict__ bhh0,
    const void* __restrict__ Wih1, const void* __restrict__ Whh1,
    const void* __restrict__ bih1, const void* __restrict__ bhh1,
    const void* __restrict__ Wfc,  const void* __restrict__ bfc,
    void* __restrict__ outv)
{
    __shared__ float xbuf[BROWS * XPAD];   // staged x, f32, padded stride
    // h exchange: [parity][quarter tau][lane], ui2 = 4 bf16 in frag layout.
    __shared__ ui2   hAq[2][4][64];
    __shared__ ui2   hBq[2][4][64];
    __shared__ float fcb[4][16];           // FC cross-wave partials
    __shared__ int   flags[8];             // [0..3]=seqA, [4..7]=seqB

    const int tid   = threadIdx.x;
    const int wv    = tid >> 6;            // 0..7
    const int layer = wv >> 2;             // 0 = GRU0 waves, 1 = GRU1 waves
    const int tau   = wv & 3;              // weight tile this wave owns
    const int l  = tid & 63;
    const int b  = l & 15;                 // batch row (MFMA D column)
    const int hp = l >> 4;                 // k-group (MFMA D row block)
    const int am = l & 15;                 // A-operand row this lane loads
    const long row0 = (long)blockIdx.x * BROWS;

    volatile int* seqA = (volatile int*)&flags[0];
    volatile int* seqB = (volatile int*)&flags[4];

    // dtype detection (uniform): fp32 misread as bf16 -> mantissa-noise
    // exponents in even ushort slots; true bf16 never exceeds exp 150.
    bool f32 = false;
    {
        const ushort_t* xs = (const ushort_t*)xv;
        for (int j = 0; j < 64; ++j){
            int e = (xs[2 * j] >> 7) & 0xFF;
            if (e > 150) f32 = true;
        }
    }

    // zero exchange buffers (h(-1) = 0, h(-2) = 0) and flags
    {
        ui2 z = {0u, 0u};
        ui2* pa = &hAq[0][0][0];
        ui2* pb = &hBq[0][0][0];
        for (int k = tid; k < 2 * 4 * 64; k += 512){ pa[k] = z; pb[k] = z; }
        if (tid < 8) flags[tid] = 0;
    }
    // stage x: 16 rows x 512, all 8 waves cooperate, convert to f32
    if (f32){
        for (int idx = tid; idx < BROWS * (T_LEN / 4); idx += 512){
            const int r = idx >> 7, sg = idx & 127;
            f32x4 v = ((const f32x4*)((const float*)xv + (row0 + r) * T_LEN))[sg];
            #pragma unroll
            for (int j = 0; j < 4; ++j) xbuf[r * XPAD + sg * 4 + j] = v[j];
        }
    } else {
        for (int idx = tid; idx < BROWS * (T_LEN / 8); idx += 512){
            const int r = idx >> 6, sg = idx & 63;
            us8 v = ((const us8*)((const ushort_t*)xv + (row0 + r) * T_LEN))[sg];
            #pragma unroll
            for (int j = 0; j < 8; ++j) xbuf[r * XPAD + sg * 8 + j] = bf2f(v[j]);
        }
    }

    const float gsc0 = LOG2E, gsc2 = 2.0f * LOG2E;

    // ---- weight / bias setup (per wave role) ----
    // Permuted gate row for tile tau:
    //   grow(g) = g*64 + 32*(tau>>1) + 8*(am>>2) + 4*(tau&1) + (am&3)
    // Lane's D outputs land at h-col hc(r) = hb0 + r,
    //   hb0 = 32*(tau>>1) + 8*hp + 4*(tau&1)  -- the ui2 quarter published.
    bf16x8 wA[3][2];                       // L0: Whh0. L1: Wih1.
    bf16x8 wH[3][2];                       // L1 only: Whh1.
    f32x4 cbR, cbZ, cbNx, cbNh;
    f32x4 cwR, cwZ, cwN;                   // L0 only: scalar-x weights
    const void* Wihp = layer ? Wih1 : Wih0;
    const void* Whhp = layer ? Whh1 : Whh0;
    const void* bihp = layer ? bih1 : bih0;
    const void* bhhp = layer ? bhh1 : bhh0;
    const int hb0 = 32 * (tau >> 1) + 8 * hp + 4 * (tau & 1);
    #pragma unroll
    for (int g = 0; g < 3; ++g){
        const float sc = (g == 2) ? gsc2 : gsc0;
        const int grow = g * 64 + 32 * (tau >> 1) + 8 * (am >> 2) + 4 * (tau & 1) + (am & 3);
        if (layer == 0){
            wA[g][0] = mk_frag(Whhp, grow, 8 * hp,      f32, sc);
            wA[g][1] = mk_frag(Whhp, grow, 32 + 8 * hp, f32, sc);
        } else {
            wA[g][0] = mk_frag(Wihp, grow, 8 * hp,      f32, sc);
            wA[g][1] = mk_frag(Wihp, grow, 32 + 8 * hp, f32, sc);
            wH[g][0] = mk_frag(Whhp, grow, 8 * hp,      f32, sc);
            wH[g][1] = mk_frag(Whhp, grow, 32 + 8 * hp, f32, sc);
        }
    }
    #pragma unroll
    for (int r = 0; r < 4; ++r){
        const int hc = hb0 + r;
        cbR[r]  = (ld_any(bihp, hc, f32)      + ld_any(bhhp, hc, f32))      * gsc0;
        cbZ[r]  = (ld_any(bihp, 64 + hc, f32) + ld_any(bhhp, 64 + hc, f32)) * gsc0;
        cbNx[r] = ld_any(bihp, 128 + hc, f32) * gsc2;
        cbNh[r] = ld_any(bhhp, 128 + hc, f32) * gsc2;
        if (layer == 0){
            cwR[r] = ld_any(Wih0, hc, f32)       * gsc0;
            cwZ[r] = ld_any(Wih0, 64 + hc, f32)  * gsc0;
            cwN[r] = ld_any(Wih0, 128 + hc, f32) * gsc2;
        }
    }

    f32x4 hS = {0.f, 0.f, 0.f, 0.f};       // f32-carried h, this wave's quarter

    __syncthreads();                       // staging + flag init complete

    if (layer == 0){
        // ================= LAYER-0 WAVES =================
        for (int t = 0; t < T_LEN; ++t){
            wait_flags(seqA, t, seqB, t - 1);
            const int p = t & 1, pr = p ^ 1;
            ui2 q0 = hAq[pr][0][l], q1 = hAq[pr][1][l];
            ui2 q2 = hAq[pr][2][l], q3 = hAq[pr][3][l];
            ui4 u0 = {q0[0], q0[1], q1[0], q1[1]};
            ui4 u1 = {q2[0], q2[1], q3[0], q3[1]};
            bf16x8 B0 = __builtin_bit_cast(bf16x8, u0);   // k 8hp..8hp+7
            bf16x8 B1 = __builtin_bit_cast(bf16x8, u1);   // k 32+8hp..+7
            const float xb = xbuf[b * XPAD + t];
            f32x4 aR, aZ, aX, aN;
            #pragma unroll
            for (int r = 0; r < 4; ++r){
                aR[r] = fmaf(xb, cwR[r], cbR[r]);
                aZ[r] = fmaf(xb, cwZ[r], cbZ[r]);
                aX[r] = fmaf(xb, cwN[r], cbNx[r]);
            }
            aR = mfma16(wA[0][0], B0, aR); aR = mfma16(wA[0][1], B1, aR);
            aZ = mfma16(wA[1][0], B0, aZ); aZ = mfma16(wA[1][1], B1, aZ);
            aN = mfma16(wA[2][0], B0, cbNh); aN = mfma16(wA[2][1], B1, aN);
            #pragma unroll
            for (int r = 0; r < 4; ++r){
                float rg = sigm2(aR[r]);
                float zg = sigm2(aZ[r]);
                float ng = tanh2(aX[r] + rg * aN[r]);
                hS[r] = ng + zg * (hS[r] - ng);
            }
            ui2 own = { cvtpk(hS[0], hS[1]), cvtpk(hS[2], hS[3]) };
            hAq[p][tau][l] = own;
            post_flag(&seqA[tau], t + 1, l);
        }
    } else {
        // ================= LAYER-1 WAVES =================
        // iter t computes hB(t-1); t = T_LEN folds the FC dot-product.
        for (int t = 1; t <= T_LEN; ++t){
            wait_flags(seqA, t, seqB, t - 1);
            const int pa = (t - 1) & 1, pb = pa ^ 1;
            ui2 a0 = hAq[pa][0][l], a1 = hAq[pa][1][l];
            ui2 a2 = hAq[pa][2][l], a3 = hAq[pa][3][l];
            ui2 c0 = hBq[pb][0][l], c1 = hBq[pb][1][l];
            ui2 c2 = hBq[pb][2][l], c3 = hBq[pb][3][l];
            ui4 ua0 = {a0[0], a0[1], a1[0], a1[1]};
            ui4 ua1 = {a2[0], a2[1], a3[0], a3[1]};
            ui4 ub0 = {c0[0], c0[1], c1[0], c1[1]};
            ui4 ub1 = {c2[0], c2[1], c3[0], c3[1]};
            bf16x8 gA0 = __builtin_bit_cast(bf16x8, ua0);
            bf16x8 gA1 = __builtin_bit_cast(bf16x8, ua1);
            bf16x8 B0  = __builtin_bit_cast(bf16x8, ub0);
            bf16x8 B1  = __builtin_bit_cast(bf16x8, ub1);
            f32x4 aR, aZ, aX, aN;
            aR = mfma16(wA[0][0], gA0, cbR);  aR = mfma16(wA[0][1], gA1, aR);
            aR = mfma16(wH[0][0], B0,  aR);   aR = mfma16(wH[0][1], B1,  aR);
            aZ = mfma16(wA[1][0], gA0, cbZ);  aZ = mfma16(wA[1][1], gA1, aZ);
            aZ = mfma16(wH[1][0], B0,  aZ);   aZ = mfma16(wH[1][1], B1,  aZ);
            aX = mfma16(wA[2][0], gA0, cbNx); aX = mfma16(wA[2][1], gA1, aX);
            aN = mfma16(wH[2][0], B0,  cbNh); aN = mfma16(wH[2][1], B1,  aN);
            if (t < T_LEN){
                #pragma unroll
                for (int r = 0; r < 4; ++r){
                    float rg = sigm2(aR[r]);
                    float zg = sigm2(aZ[r]);
                    float ng = tanh2(aX[r] + rg * aN[r]);
                    hS[r] = ng + zg * (hS[r] - ng);
                }
                ui2 own = { cvtpk(hS[0], hS[1]), cvtpk(hS[2], hS[3]) };
                hBq[pa][tau][l] = own;
                post_flag(&seqB[tau], t, l);
            } else {
                // final step: compute hB(511) and fold FC immediately
                float part = 0.0f;
                #pragma unroll
                for (int r = 0; r < 4; ++r){
                    float rg = sigm2(aR[r]);
                    float zg = sigm2(aZ[r]);
                    float ng = tanh2(aX[r] + rg * aN[r]);
                    float hf = ng + zg * (hS[r] - ng);
                    part = fmaf(ld_any(Wfc, hb0 + r, f32), hf, part);
                }
                part += __shfl_xor(part, 16);      // reduce across hp
                part += __shfl_xor(part, 32);
                if (l < 16) fcb[tau][b] = part;
            }
        }
    }

    __syncthreads();                       // fcb ready for the FC gather

    if (wv == 0 && l < 16){
        float s = fcb[0][b] + fcb[1][b] + fcb[2][b] + fcb[3][b]
                + ld_any(bfc, 0, f32);
        if (f32) ((float*)outv)[row0 + b] = s;
        else     ((ushort_t*)outv)[row0 + b] = f2bf(s);
    }
}

extern "C" void kernel_launch(void* const* d_in, const int* in_sizes, int n_in,
                              void* d_out, int out_size, void* d_ws, size_t ws_size,
                              hipStream_t stream)
{
    (void)in_sizes; (void)n_in; (void)d_ws; (void)ws_size;
    const int B = out_size;               // O = 1 -> out_size == batch
    const int nblk = B / BROWS;           // 2048/16 = 128 blocks, 8 waves each
    gru_fused<<<nblk, 512, 0, stream>>>(
        d_in[0],
        d_in[1], d_in[2], d_in[3], d_in[4],
        d_in[5], d_in[6], d_in[7], d_in[8],
        d_in[9], d_in[10],
        d_out);
}